// Round 17
// baseline (59.636 us; speedup 1.0000x reference)
//
#include <hip/hip_runtime.h>
#include <hip/hip_bf16.h>

// Problem constants (match reference)
#define T_TOK 8192
#define DDIM  1024
#define HDIM  512
#define NE    8
#define TPE   (T_TOK / NE)   // 1024 tokens per expert (static partition per reference)

typedef __attribute__((ext_vector_type(4))) float floatx4;
typedef __attribute__((ext_vector_type(8))) short bf16x8;

#define SBAR() __builtin_amdgcn_sched_barrier(0)

__device__ __forceinline__ unsigned short f2bf(float f) {
    union { float f; unsigned int u; } v;
    v.f = f;
    unsigned int u = v.u;
    unsigned int r = u + 0x7FFFu + ((u >> 16) & 1u);  // RNE
    return (unsigned short)(r >> 16);
}

// packed f32x2 -> bf16x2 (RNE), single instruction
__device__ __forceinline__ unsigned int cvt_pk_bf16(float lo, float hi) {
    unsigned int r;
    asm("v_cvt_pk_bf16_f32 %0, %1, %2" : "=v"(r) : "v"(lo), "v"(hi));
    return r;
}

// async global -> LDS, 16 bytes per lane (dest must be linear: base + lane*16)
__device__ __forceinline__ void gld_lds16(const void* g, void* l) {
    __builtin_amdgcn_global_load_lds(
        (const __attribute__((address_space(1))) unsigned int*)g,
        (__attribute__((address_space(3))) unsigned int*)l, 16, 0, 0);
}

// ---------------------------------------------------------------------------
// Kernel 0 (streaming): X*scale -> bf16 and W13 fp32 -> bf16 (round-9 form).
// Rationale (round 9 vs rounds 10-16): gemm1 with fp32-B is pinned at
// ~35-39 us by the 512 MB W13 fp32 stream; bf16-B via gld_lds measured
// ~20 us. The serialized convert cost is repaid by gemm1's B-traffic cut,
// and BM=256 (below) halves it again.
// ---------------------------------------------------------------------------
__global__ __launch_bounds__(256)
void convert_kernel(const float* __restrict__ X, const float* __restrict__ S,
                    const float* __restrict__ W13,
                    unsigned short* __restrict__ Xb,
                    unsigned short* __restrict__ W13b)
{
    const int NTX  = (T_TOK * DDIM) / 4;           // 2,097,152 float4 chunks
    const int NT13 = (NE * 2 * HDIM * DDIM) / 4;   // 2,097,152
    const int stride = gridDim.x * blockDim.x;
    for (int i = blockIdx.x * blockDim.x + threadIdx.x; i < NTX + NT13; i += stride) {
        float4 v;
        ushort4* dst;
        if (i < NTX) {
            int row = i >> 8;            // D/4 = 256 chunks per row
            int c4  = i & 255;
            v = reinterpret_cast<const float4*>(X)[i];
            float sc = S[row * (DDIM / 32) + (c4 >> 3)];
            v.x *= sc; v.y *= sc; v.z *= sc; v.w *= sc;
            dst = (ushort4*)Xb + i;
        } else {
            int j = i - NTX;
            v = reinterpret_cast<const float4*>(W13)[j];
            dst = (ushort4*)W13b + j;
        }
        ushort4 b;
        b.x = f2bf(v.x); b.y = f2bf(v.y); b.z = f2bf(v.z); b.w = f2bf(v.w);
        *dst = b;
    }
}

// XCD-aware swizzles (nwg % 8 == 0 -> bijective)
__device__ __forceinline__ int xcd_swizzle_512(int raw) {
    return (raw & 7) * 64 + (raw >> 3);
}
__device__ __forceinline__ int xcd_swizzle_256(int raw) {
    return (raw & 7) * 32 + (raw >> 3);
}

// LDS tile layout: [rows][8 slots of 16B]. Bank-conflict swizzle (T2/G21):
//   phys 16B-slot = logical_slot ^ (row & 7)
//   - gld_lds path: LDS dest LINEAR, global SOURCE slot pre-permuted.
//   - ds_read applies the same XOR.

// ---------------------------------------------------------------------------
// Kernel 1: h = silu(Xb W1^T) * (Xb W3^T).  ALL-bf16, dual gld_lds.
// BM=256, BN=64 (w1+w3 paired => 128 B rows), BK=64, 512 thr (8 waves 4Mx2N).
// B traffic: W13b 32 MB x 4 mt-re-reads = 128 MB (vs round 9's 256 MB at
// BM=128, vs rounds 10-16's 512 MB fp32).
// Per thread per K-step: 4 gld_lds (A: 256x64) + 2 gld_lds (B: 128x64) = 6 VM.
// Round-6 proven 2-barrier prefetch: STAGE(t+1); vmcnt(6) [tile t landed];
// s_barrier; COMPUTE(t); s_barrier.
// LDS: sA dbuf 64 KB + sB dbuf 32 KB = 96 KB -> 1 block/CU.
// grid = 8e * 4mt * 8nt = 256 blocks.
// ---------------------------------------------------------------------------
__global__ __launch_bounds__(512, 2)
void gemm1_silu_kernel(const unsigned short* __restrict__ Xb,
                       const unsigned short* __restrict__ W13b,
                       __hip_bfloat16* __restrict__ Hout)
{
    const int bid = xcd_swizzle_256(blockIdx.x);
    const int e  = bid >> 5;
    const int mt = (bid >> 3) & 3;    // token tile (256 rows)
    const int nt = bid & 7;           // h tile (64 cols)
    const int tok0 = e * TPE + mt * 256;
    const unsigned short* __restrict__ We = W13b + (size_t)e * (2 * HDIM) * DDIM;

    __shared__ __hip_bfloat16 sA[2][256][64];   // 64 KB
    __shared__ __hip_bfloat16 sB[2][128][64];   // 32 KB

    const int tid  = threadIdx.x;
    const int lane = tid & 63;
    const int wave = tid >> 6;   // 0..7
    const int wr = wave >> 1;    // 0..3 (M quarter: 64 rows)
    const int wc = wave & 1;     // 0..1 (N: 32 cols each)
    const int lr = lane & 15;
    const int sw0 = ((lane >> 4) ^ (lane & 7));

    floatx4 acc1[4][2] = {};
    floatx4 acc3[4][2] = {};

    // A staging: 256x64 bf16 = 2048 x 16B chunks / 512 thr = 4 each
    const int srowA = tid >> 3;                          // 0..63
    const int dcolA = (tid & 7) * 8;                     // LDS linear dest
    const int gcolA = ((tid & 7) ^ (srowA & 7)) * 8;     // pre-swizzled source
    // B staging: 128x64 bf16 = 1024 x 16B chunks / 512 thr = 2 each
    //   chunk c = tid (row 0..63 -> w1) and c = tid+512 (row 64..127 -> w3)
    const int srowB = tid >> 3;                          // 0..63
    const int dcolB = (tid & 7) * 8;
    const int gcolB = ((tid & 7) ^ (srowB & 7)) * 8;     // row&7 same for both chunks

    auto STAGE = [&](int kk, int buf) {      // 6 VM ops (all gld_lds)
        const int k0 = kk * 64;
        #pragma unroll
        for (int j = 0; j < 4; ++j) {
            int row = srowA + j * 64;        // row&7 const under +64
            gld_lds16(&Xb[(size_t)(tok0 + row) * DDIM + k0 + gcolA],
                      &sA[buf][row][dcolA]);
        }
        // B chunk 0: w1 rows [nt*64 + srowB]
        gld_lds16(&We[(size_t)(nt * 64 + srowB) * DDIM + k0 + gcolB],
                  &sB[buf][srowB][dcolB]);
        // B chunk 1: w3 rows -> sB rows 64..127
        gld_lds16(&We[(size_t)(HDIM + nt * 64 + srowB) * DDIM + k0 + gcolB],
                  &sB[buf][64 + srowB][dcolB]);
    };
    auto COMPUTE = [&](int buf) {
        #pragma unroll
        for (int ks = 0; ks < 2; ++ks) {
            const int rc = (sw0 ^ (ks << 2)) << 3;   // swizzled read col (elems)
            bf16x8 a[4], b1[2], b3[2];
            #pragma unroll
            for (int m = 0; m < 4; ++m)
                a[m] = *reinterpret_cast<const bf16x8*>(&sA[buf][wr * 64 + m * 16 + lr][rc]);
            #pragma unroll
            for (int n = 0; n < 2; ++n) {
                b1[n] = *reinterpret_cast<const bf16x8*>(&sB[buf][wc * 32 + n * 16 + lr][rc]);
                b3[n] = *reinterpret_cast<const bf16x8*>(&sB[buf][64 + wc * 32 + n * 16 + lr][rc]);
            }
            #pragma unroll
            for (int m = 0; m < 4; ++m)
                #pragma unroll
                for (int n = 0; n < 2; ++n) {
                    acc1[m][n] = __builtin_amdgcn_mfma_f32_16x16x32_bf16(a[m], b1[n], acc1[m][n], 0, 0, 0);
                    acc3[m][n] = __builtin_amdgcn_mfma_f32_16x16x32_bf16(a[m], b3[n], acc3[m][n], 0, 0, 0);
                }
        }
    };

    STAGE(0, 0);
    for (int kk = 0; kk < DDIM / 64 - 1; ++kk) {       // kk = 0..14
        STAGE(kk + 1, (kk + 1) & 1);
        asm volatile("s_waitcnt vmcnt(6)" ::: "memory");  // tile kk landed
        SBAR();
        __builtin_amdgcn_s_barrier();
        COMPUTE(kk & 1);
        __builtin_amdgcn_s_barrier();                  // guard buf before next STAGE
    }
    asm volatile("s_waitcnt vmcnt(0)" ::: "memory");
    SBAR();
    __builtin_amdgcn_s_barrier();
    COMPUTE(1);                                        // tile 15

    // ---- epilogue: h = silu(h1) * h3 -> bf16
    const int hcol0 = nt * 64 + wc * 32;
    #pragma unroll
    for (int m = 0; m < 4; ++m) {
        #pragma unroll
        for (int n = 0; n < 2; ++n) {
            #pragma unroll
            for (int i = 0; i < 4; ++i) {
                int row = tok0 + wr * 64 + m * 16 + (lane >> 4) * 4 + i;
                int col = hcol0 + n * 16 + (lane & 15);
                float h1 = acc1[m][n][i];
                float h3 = acc3[m][n][i];
                float sig = 1.0f / (1.0f + __expf(-h1));
                Hout[(size_t)row * HDIM + col] = __float2bfloat16(h1 * sig * h3);
            }
        }
    }
}

// ---------------------------------------------------------------------------
// Kernel 2: out = h W2^T.  (round-11..16 form, near its L2/HBM floor; unchanged)
// A = Hb bf16 via gld_lds; B = W2 fp32->bf16 reg-staged depth-2, write-late.
// ---------------------------------------------------------------------------
__global__ __launch_bounds__(256, 2)
void gemm2_kernel(const __hip_bfloat16* __restrict__ Hin,
                  const float* __restrict__ W2,
                  float* __restrict__ Out)
{
    const int bid = xcd_swizzle_512(blockIdx.x);
    const int e  = bid >> 6;
    const int nt = (bid >> 3) & 7;    // d tile -- major (W2 tile reused)
    const int mt = bid & 7;           // token tile -- fastest (stream Hb)
    const int tok0 = e * TPE + mt * 128;
    const float* __restrict__ We = W2 + (size_t)e * DDIM * HDIM;

    __shared__ __hip_bfloat16 sA[2][128][64];
    __shared__ __hip_bfloat16 sB[2][128][64];

    const int tid  = threadIdx.x;
    const int lane = tid & 63;
    const int wave = tid >> 6;
    const int wr = wave >> 1;
    const int wc = wave & 1;
    const int lr = lane & 15;
    const int sw0 = ((lane >> 4) ^ (lane & 7));

    floatx4 acc[4][4] = {};

    const int srow0 = (tid >> 3);
    const int c8    = (tid & 7) * 8;
    const int dcol  = (tid & 7) * 8;
    const int swcol = ((tid & 7) ^ (srow0 & 7)) * 8;

    float4 rB0[8], rB1[8];

    auto LOADB = [&](int kk, float4* rB) {  // 8 VM ops
        const int k0 = kk * 64;
        #pragma unroll
        for (int j = 0; j < 4; ++j) {
            int row = srow0 + j * 32;
            const float* p = &We[(size_t)(nt * 128 + row) * HDIM + k0 + c8];
            rB[2*j]   = *reinterpret_cast<const float4*>(p);
            rB[2*j+1] = *reinterpret_cast<const float4*>(p + 4);
        }
    };
    auto STAGEA = [&](int kk, int buf) {    // 4 VM ops (gld_lds)
        const int k0 = kk * 64;
        #pragma unroll
        for (int j = 0; j < 4; ++j) {
            int row = srow0 + j * 32;
            gld_lds16(&Hin[(size_t)(tok0 + row) * HDIM + k0 + swcol],
                      &sA[buf][row][dcol]);
        }
    };
    auto WRITEB = [&](int buf, const float4* rB) {
        #pragma unroll
        for (int j = 0; j < 4; ++j) {
            int row = srow0 + j * 32;
            uint4 w;
            w.x = cvt_pk_bf16(rB[2*j].x,   rB[2*j].y);
            w.y = cvt_pk_bf16(rB[2*j].z,   rB[2*j].w);
            w.z = cvt_pk_bf16(rB[2*j+1].x, rB[2*j+1].y);
            w.w = cvt_pk_bf16(rB[2*j+1].z, rB[2*j+1].w);
            *reinterpret_cast<uint4*>(&sB[buf][row][swcol]) = w;
        }
    };
    auto COMPUTE = [&](int buf) {
        #pragma unroll
        for (int ks = 0; ks < 2; ++ks) {
            const int rc = (sw0 ^ (ks << 2)) << 3;
            bf16x8 a[4], b[4];
            #pragma unroll
            for (int m = 0; m < 4; ++m)
                a[m] = *reinterpret_cast<const bf16x8*>(&sA[buf][wr * 64 + m * 16 + lr][rc]);
            #pragma unroll
            for (int n = 0; n < 4; ++n)
                b[n] = *reinterpret_cast<const bf16x8*>(&sB[buf][wc * 64 + n * 16 + lr][rc]);
            #pragma unroll
            for (int m = 0; m < 4; ++m)
                #pragma unroll
                for (int n = 0; n < 4; ++n)
                    acc[m][n] = __builtin_amdgcn_mfma_f32_16x16x32_bf16(a[m], b[n], acc[m][n], 0, 0, 0);
        }
    };

    // ---- prologue
    LOADB(0, rB0);  SBAR();
    STAGEA(0, 0);   SBAR();
    LOADB(1, rB1);  SBAR();
    asm volatile("s_waitcnt vmcnt(12)" ::: "memory");  // LOADB(0) done
    SBAR();
    WRITEB(0, rB0); SBAR();
    asm volatile("s_waitcnt vmcnt(8) lgkmcnt(0)" ::: "memory");
    SBAR();
    __builtin_amdgcn_s_barrier();

    // ---- steady phases 0..5
    for (int t = 0; t < HDIM / 64 - 2; t += 2) {        // t = 0,2,4
        // phase t (buf 0)
        STAGEA(t + 1, 1);   SBAR();
        LOADB(t + 2, rB0);  SBAR();
        COMPUTE(0);
        asm volatile("s_waitcnt vmcnt(12)" ::: "memory");  // LOADB(t+1) -> rB1
        SBAR();
        WRITEB(1, rB1);     SBAR();
        asm volatile("s_waitcnt vmcnt(8) lgkmcnt(0)" ::: "memory");
        SBAR();
        __builtin_amdgcn_s_barrier();
        // phase t+1 (buf 1)
        STAGEA(t + 2, 0);   SBAR();
        LOADB(t + 3, rB1);  SBAR();
        COMPUTE(1);
        asm volatile("s_waitcnt vmcnt(12)" ::: "memory");  // LOADB(t+2) -> rB0
        SBAR();
        WRITEB(0, rB0);     SBAR();
        asm volatile("s_waitcnt vmcnt(8) lgkmcnt(0)" ::: "memory");
        SBAR();
        __builtin_amdgcn_s_barrier();
    }

    // ---- phase 6 (buf 0): leftover LOADB(7) in rB1
    STAGEA(7, 1);   SBAR();
    COMPUTE(0);
    asm volatile("s_waitcnt vmcnt(4)" ::: "memory");   // LOADB(7) done
    SBAR();
    WRITEB(1, rB1); SBAR();
    asm volatile("s_waitcnt vmcnt(0) lgkmcnt(0)" ::: "memory");
    SBAR();
    __builtin_amdgcn_s_barrier();
    // ---- phase 7 (buf 1)
    COMPUTE(1);

    const int dcol0 = nt * 128 + wc * 64;
    #pragma unroll
    for (int m = 0; m < 4; ++m) {
        #pragma unroll
        for (int n = 0; n < 4; ++n) {
            #pragma unroll
            for (int i = 0; i < 4; ++i) {
                int row = tok0 + wr * 64 + m * 16 + (lane >> 4) * 4 + i;
                int col = dcol0 + n * 16 + (lane & 15);
                Out[(size_t)row * DDIM + col] = acc[m][n][i];
            }
        }
    }
}

extern "C" void kernel_launch(void* const* d_in, const int* in_sizes, int n_in,
                              void* d_out, int out_size, void* d_ws, size_t ws_size,
                              hipStream_t stream) {
    const float* X   = (const float*)d_in[0];   // (T, D) fp32
    const float* S   = (const float*)d_in[1];   // (T, D/32) fp32
    const float* W13 = (const float*)d_in[4];   // (E, 2H, D) fp32
    const float* W2  = (const float*)d_in[5];   // (E, D, H) fp32
    float* Out = (float*)d_out;                 // (T, D) fp32

    // workspace layout (bytes):
    //   [0, 16Mi)    W13b bf16 (E*2H*D)
    //   [16Mi, 24Mi) Hb   bf16 (T*H)
    // Xb (T*D bf16 = 16 MiB) lives in d_out's first half: gemm1 consumes it,
    // then gemm2 overwrites all of d_out with the final fp32 output.
    unsigned short* W13b = (unsigned short*)d_ws;
    __hip_bfloat16* Hb   = (__hip_bfloat16*)(W13b + (size_t)NE * 2 * HDIM * DDIM);
    unsigned short* Xb   = (unsigned short*)d_out;

    convert_kernel<<<2048, 256, 0, stream>>>(X, S, W13, Xb, W13b);
    gemm1_silu_kernel<<<NE * 4 * 8, 512, 0, stream>>>(Xb, W13b, Hb);
    gemm2_kernel<<<NE * 8 * 8, 256, 0, stream>>>(Hb, W2, Out);
}

// Round 18
// 55.487 us; speedup vs baseline: 1.0748x; 1.0748x over previous
//
#include <hip/hip_runtime.h>
#include <hip/hip_bf16.h>

// Problem constants (match reference)
#define T_TOK 8192
#define DDIM  1024
#define HDIM  512
#define NE    8
#define TPE   (T_TOK / NE)   // 1024 tokens per expert (static partition per reference)

typedef __attribute__((ext_vector_type(4))) float floatx4;
typedef __attribute__((ext_vector_type(8))) short bf16x8;

#define SBAR() __builtin_amdgcn_sched_barrier(0)

__device__ __forceinline__ unsigned short f2bf(float f) {
    union { float f; unsigned int u; } v;
    v.f = f;
    unsigned int u = v.u;
    unsigned int r = u + 0x7FFFu + ((u >> 16) & 1u);  // RNE
    return (unsigned short)(r >> 16);
}

// packed f32x2 -> bf16x2 (RNE), single instruction
__device__ __forceinline__ unsigned int cvt_pk_bf16(float lo, float hi) {
    unsigned int r;
    asm("v_cvt_pk_bf16_f32 %0, %1, %2" : "=v"(r) : "v"(lo), "v"(hi));
    return r;
}

// async global -> LDS, 16 bytes per lane (dest must be linear: base + lane*16)
__device__ __forceinline__ void gld_lds16(const void* g, void* l) {
    __builtin_amdgcn_global_load_lds(
        (const __attribute__((address_space(1))) unsigned int*)g,
        (__attribute__((address_space(3))) unsigned int*)l, 16, 0, 0);
}

// ---------------------------------------------------------------------------
// Kernel 0 (streaming): X*scale -> bf16 only (48 MB round trip, BW floor).
// ---------------------------------------------------------------------------
__global__ __launch_bounds__(256)
void convert_x_kernel(const float* __restrict__ X, const float* __restrict__ S,
                      unsigned short* __restrict__ Xb)
{
    const int NTX = (T_TOK * DDIM) / 4;            // 2,097,152 float4 chunks
    const int stride = gridDim.x * blockDim.x;
    for (int i = blockIdx.x * blockDim.x + threadIdx.x; i < NTX; i += stride) {
        int row = i >> 8;            // D/4 = 256 chunks per row
        int c4  = i & 255;
        float4 v = reinterpret_cast<const float4*>(X)[i];
        float sc = S[row * (DDIM / 32) + (c4 >> 3)];
        ushort4 b;
        b.x = f2bf(v.x * sc); b.y = f2bf(v.y * sc);
        b.z = f2bf(v.z * sc); b.w = f2bf(v.w * sc);
        reinterpret_cast<ushort4*>(Xb)[i] = b;
    }
}

// XCD-aware swizzles (nwg % 8 == 0 -> bijective)
__device__ __forceinline__ int xcd_swizzle_512(int raw) {
    return (raw & 7) * 64 + (raw >> 3);
}
__device__ __forceinline__ int xcd_swizzle_256(int raw) {
    return (raw & 7) * 32 + (raw >> 3);
}

// LDS tile layout: [rows][8 slots of 16B]. Bank-conflict swizzle (T2/G21):
//   phys 16B-slot = logical_slot ^ (row & 7)
//   - gld_lds path: LDS dest LINEAR, global SOURCE slot pre-permuted.
//   - reg-staged path: ds_write directly to the swizzled slot.
//   - ds_read applies the same XOR.

// ---------------------------------------------------------------------------
// Kernel 1: h = silu(Xb W1^T) * (Xb W3^T).  BM=256, BN=64, BK=64, 512 thr.
// ROUND-18 CHANGE vs round 15 (best, 54.4): block order within an expert is
// now mt-FASTEST (nt-major). Mechanism: the dominant stream is fp32 W13
// (2x A bytes). nt-fastest order made the rotating XCD set = Xb-tile 0.5 MB
// + W13-expert 4 MB = 4.5 MB > 4 MB L2 -> every B load was an L3 access.
// mt-fastest: 4 mt-blocks share a 0.5 MB W13 slice; Xb expert slice (2 MB)
// stays L2-resident -> rotating 2.5 MB < 4 MB. This is exactly gemm2's
// proven cache regime (its fp32 B-slice is L2-resident and it runs at 2.9x
// gemm1's per-FLOP speed with the same schedule).
// A = Xb bf16 via gld_lds (sA dbuf 64 KB); B = W13 fp32 reg-staged depth-2
// (rB0/rB1, 4 float4 each), cvt_pk -> swizzled ds_write (sB dbuf 32 KB).
// LDS 96 KB -> 1 block/CU, 8 waves. Write-late single-barrier phase:
//   STAGEA(t+1,buf^1)[4] ; LOADB(t+2)[4] ; COMPUTE(t) ;
//   vmcnt(8)  [LOADB(t+1) landed] ; WRITEB(t+1) ;
//   vmcnt(4)+lgkmcnt(0) [STAGEA(t+1) done; LOADB(t+2) airborne] ; s_barrier
// grid = 8e * 8nt * 4mt = 256 blocks.
// ---------------------------------------------------------------------------
__global__ __launch_bounds__(512, 2)
void gemm1_silu_kernel(const unsigned short* __restrict__ Xb,
                       const float* __restrict__ W13,
                       __hip_bfloat16* __restrict__ Hout)
{
    const int bid = xcd_swizzle_256(blockIdx.x);
    const int e  = bid >> 5;
    const int nt = (bid >> 2) & 7;    // h tile (64 cols)     -- major
    const int mt = bid & 3;           // token tile (256 rows) -- fastest
    const int tok0 = e * TPE + mt * 256;
    const float* __restrict__ We = W13 + (size_t)e * (2 * HDIM) * DDIM;

    __shared__ __hip_bfloat16 sA[2][256][64];   // 64 KB
    __shared__ __hip_bfloat16 sB[2][128][64];   // 32 KB

    const int tid  = threadIdx.x;
    const int lane = tid & 63;
    const int wave = tid >> 6;   // 0..7
    const int wr = wave >> 1;    // 0..3 (M quarter: 64 rows)
    const int wc = wave & 1;     // 0..1 (N: 32 cols each)
    const int lr = lane & 15;
    const int sw0 = ((lane >> 4) ^ (lane & 7));

    floatx4 acc1[4][2] = {};
    floatx4 acc3[4][2] = {};

    // A staging: 256x64 bf16 = 2048 x 16B chunks / 512 thr = 4 each
    const int srowA = tid >> 3;                          // 0..63
    const int dcolA = (tid & 7) * 8;                     // LDS linear dest
    const int gcolA = ((tid & 7) ^ (srowA & 7)) * 8;     // pre-swizzled source
    // B load: 128 rows x 16 float4 / 512 thr = 4 each
    const int srowB = tid >> 4;                          // 0..31
    const int f4    = tid & 15;                          // float4 slot in row
    const int bcol  = f4 * 4;                            // fp32 col

    float4 rB0[4], rB1[4];

    auto LOADB = [&](int kk, float4* rB) {   // 4 VM ops, fp32 W13 (w1|w3 rows)
        const int k0 = kk * 64;
        #pragma unroll
        for (int j = 0; j < 4; ++j) {
            int row = srowB + j * 32;        // 0..127; row&7 const under +32
            int wrow = (j < 2) ? (nt * 64 + row)                 // w1 rows
                               : (HDIM + nt * 64 + (row - 64));  // w3 rows
            rB[j] = *reinterpret_cast<const float4*>(
                        &We[(size_t)wrow * DDIM + k0 + bcol]);
        }
    };
    auto STAGEA = [&](int kk, int buf) {     // 4 VM ops (gld_lds)
        const int k0 = kk * 64;
        #pragma unroll
        for (int j = 0; j < 4; ++j) {
            int row = srowA + j * 64;        // row&7 const under +64
            gld_lds16(&Xb[(size_t)(tok0 + row) * DDIM + k0 + gcolA],
                      &sA[buf][row][dcolA]);
        }
    };
    auto WRITEB = [&](int buf, const float4* rB) {   // cvt + swizzled ds_write_b64
        #pragma unroll
        for (int j = 0; j < 4; ++j) {
            int row = srowB + j * 32;
            uint2 w;
            w.x = cvt_pk_bf16(rB[j].x, rB[j].y);
            w.y = cvt_pk_bf16(rB[j].z, rB[j].w);
            char* base = reinterpret_cast<char*>(&sB[buf][row][0]);
            int off = (((f4 >> 1) ^ (row & 7)) << 4) + ((f4 & 1) << 3);
            *reinterpret_cast<uint2*>(base + off) = w;
        }
    };
    auto COMPUTE_KS = [&](int buf, int ks) {
        const int rc = (sw0 ^ (ks << 2)) << 3;   // swizzled read col
        bf16x8 a[4], b1[2], b3[2];
        #pragma unroll
        for (int m = 0; m < 4; ++m)
            a[m] = *reinterpret_cast<const bf16x8*>(&sA[buf][wr * 64 + m * 16 + lr][rc]);
        #pragma unroll
        for (int n = 0; n < 2; ++n) {
            b1[n] = *reinterpret_cast<const bf16x8*>(&sB[buf][wc * 32 + n * 16 + lr][rc]);
            b3[n] = *reinterpret_cast<const bf16x8*>(&sB[buf][64 + wc * 32 + n * 16 + lr][rc]);
        }
        #pragma unroll
        for (int m = 0; m < 4; ++m)
            #pragma unroll
            for (int n = 0; n < 2; ++n) {
                acc1[m][n] = __builtin_amdgcn_mfma_f32_16x16x32_bf16(a[m], b1[n], acc1[m][n], 0, 0, 0);
                acc3[m][n] = __builtin_amdgcn_mfma_f32_16x16x32_bf16(a[m], b3[n], acc3[m][n], 0, 0, 0);
            }
    };

    // ---- prologue: VM order [LOADB(0) 4][STAGEA(0) 4][LOADB(1) 4]
    LOADB(0, rB0);  SBAR();
    STAGEA(0, 0);   SBAR();
    LOADB(1, rB1);  SBAR();
    asm volatile("s_waitcnt vmcnt(8)" ::: "memory");   // LOADB(0) done
    SBAR();
    WRITEB(0, rB0); SBAR();
    asm volatile("s_waitcnt vmcnt(4) lgkmcnt(0)" ::: "memory"); // STAGEA(0)+writes
    SBAR();
    __builtin_amdgcn_s_barrier();
    // entering steady state: outstanding VM = LOADB(1) [4]

    // ---- steady phases 0..13 (even/odd pairs; static rB names)
    for (int t = 0; t < DDIM / 64 - 2; t += 2) {        // t = 0,2,...,12
        // phase t (buf 0): rB1 holds tile t+1 (in flight)
        STAGEA(t + 1, 1);   SBAR();
        LOADB(t + 2, rB0);  SBAR();
        COMPUTE_KS(0, 0);
        COMPUTE_KS(0, 1);
        asm volatile("s_waitcnt vmcnt(8)" ::: "memory");  // LOADB(t+1) -> rB1 ready
        SBAR();
        WRITEB(1, rB1);     SBAR();
        asm volatile("s_waitcnt vmcnt(4) lgkmcnt(0)" ::: "memory"); // STAGEA(t+1)
        SBAR();
        __builtin_amdgcn_s_barrier();
        // phase t+1 (buf 1): rB0 holds tile t+2 (in flight)
        STAGEA(t + 2, 0);   SBAR();
        LOADB(t + 3, rB1);  SBAR();
        COMPUTE_KS(1, 0);
        COMPUTE_KS(1, 1);
        asm volatile("s_waitcnt vmcnt(8)" ::: "memory");  // LOADB(t+2) -> rB0 ready
        SBAR();
        WRITEB(0, rB0);     SBAR();
        asm volatile("s_waitcnt vmcnt(4) lgkmcnt(0)" ::: "memory"); // STAGEA(t+2)
        SBAR();
        __builtin_amdgcn_s_barrier();
    }

    // ---- phase 14 (buf 0): rB1 holds LOADB(15); no more LOADB
    STAGEA(15, 1);    SBAR();
    COMPUTE_KS(0, 0);
    COMPUTE_KS(0, 1);
    asm volatile("s_waitcnt vmcnt(4)" ::: "memory");   // LOADB(15) done
    SBAR();
    WRITEB(1, rB1);   SBAR();
    asm volatile("s_waitcnt vmcnt(0) lgkmcnt(0)" ::: "memory"); // STAGEA(15)
    SBAR();
    __builtin_amdgcn_s_barrier();
    // ---- phase 15 (buf 1)
    COMPUTE_KS(1, 0);
    COMPUTE_KS(1, 1);

    // ---- epilogue: h = silu(h1) * h3 -> bf16
    const int hcol0 = nt * 64 + wc * 32;
    #pragma unroll
    for (int m = 0; m < 4; ++m) {
        #pragma unroll
        for (int n = 0; n < 2; ++n) {
            #pragma unroll
            for (int i = 0; i < 4; ++i) {
                int row = tok0 + wr * 64 + m * 16 + (lane >> 4) * 4 + i;
                int col = hcol0 + n * 16 + (lane & 15);
                float h1 = acc1[m][n][i];
                float h3 = acc3[m][n][i];
                float sig = 1.0f / (1.0f + __expf(-h1));
                Hout[(size_t)row * HDIM + col] = __float2bfloat16(h1 * sig * h3);
            }
        }
    }
}

// ---------------------------------------------------------------------------
// Kernel 2: out = h W2^T.  (round-11..17 form, near its L2/HBM floor; unchanged)
// A = Hb bf16 via gld_lds; B = W2 fp32->bf16 reg-staged depth-2, write-late.
// ---------------------------------------------------------------------------
__global__ __launch_bounds__(256, 2)
void gemm2_kernel(const __hip_bfloat16* __restrict__ Hin,
                  const float* __restrict__ W2,
                  float* __restrict__ Out)
{
    const int bid = xcd_swizzle_512(blockIdx.x);
    const int e  = bid >> 6;
    const int nt = (bid >> 3) & 7;    // d tile -- major (W2 tile reused)
    const int mt = bid & 7;           // token tile -- fastest (stream Hb)
    const int tok0 = e * TPE + mt * 128;
    const float* __restrict__ We = W2 + (size_t)e * DDIM * HDIM;

    __shared__ __hip_bfloat16 sA[2][128][64];
    __shared__ __hip_bfloat16 sB[2][128][64];

    const int tid  = threadIdx.x;
    const int lane = tid & 63;
    const int wave = tid >> 6;
    const int wr = wave >> 1;
    const int wc = wave & 1;
    const int lr = lane & 15;
    const int sw0 = ((lane >> 4) ^ (lane & 7));

    floatx4 acc[4][4] = {};

    const int srow0 = (tid >> 3);
    const int c8    = (tid & 7) * 8;
    const int dcol  = (tid & 7) * 8;
    const int swcol = ((tid & 7) ^ (srow0 & 7)) * 8;

    float4 rB0[8], rB1[8];

    auto LOADB = [&](int kk, float4* rB) {  // 8 VM ops
        const int k0 = kk * 64;
        #pragma unroll
        for (int j = 0; j < 4; ++j) {
            int row = srow0 + j * 32;
            const float* p = &We[(size_t)(nt * 128 + row) * HDIM + k0 + c8];
            rB[2*j]   = *reinterpret_cast<const float4*>(p);
            rB[2*j+1] = *reinterpret_cast<const float4*>(p + 4);
        }
    };
    auto STAGEA = [&](int kk, int buf) {    // 4 VM ops (gld_lds)
        const int k0 = kk * 64;
        #pragma unroll
        for (int j = 0; j < 4; ++j) {
            int row = srow0 + j * 32;
            gld_lds16(&Hin[(size_t)(tok0 + row) * HDIM + k0 + swcol],
                      &sA[buf][row][dcol]);
        }
    };
    auto WRITEB = [&](int buf, const float4* rB) {
        #pragma unroll
        for (int j = 0; j < 4; ++j) {
            int row = srow0 + j * 32;
            uint4 w;
            w.x = cvt_pk_bf16(rB[2*j].x,   rB[2*j].y);
            w.y = cvt_pk_bf16(rB[2*j].z,   rB[2*j].w);
            w.z = cvt_pk_bf16(rB[2*j+1].x, rB[2*j+1].y);
            w.w = cvt_pk_bf16(rB[2*j+1].z, rB[2*j+1].w);
            *reinterpret_cast<uint4*>(&sB[buf][row][swcol]) = w;
        }
    };
    auto COMPUTE = [&](int buf) {
        #pragma unroll
        for (int ks = 0; ks < 2; ++ks) {
            const int rc = (sw0 ^ (ks << 2)) << 3;
            bf16x8 a[4], b[4];
            #pragma unroll
            for (int m = 0; m < 4; ++m)
                a[m] = *reinterpret_cast<const bf16x8*>(&sA[buf][wr * 64 + m * 16 + lr][rc]);
            #pragma unroll
            for (int n = 0; n < 4; ++n)
                b[n] = *reinterpret_cast<const bf16x8*>(&sB[buf][wc * 64 + n * 16 + lr][rc]);
            #pragma unroll
            for (int m = 0; m < 4; ++m)
                #pragma unroll
                for (int n = 0; n < 4; ++n)
                    acc[m][n] = __builtin_amdgcn_mfma_f32_16x16x32_bf16(a[m], b[n], acc[m][n], 0, 0, 0);
        }
    };

    // ---- prologue
    LOADB(0, rB0);  SBAR();
    STAGEA(0, 0);   SBAR();
    LOADB(1, rB1);  SBAR();
    asm volatile("s_waitcnt vmcnt(12)" ::: "memory");  // LOADB(0) done
    SBAR();
    WRITEB(0, rB0); SBAR();
    asm volatile("s_waitcnt vmcnt(8) lgkmcnt(0)" ::: "memory");
    SBAR();
    __builtin_amdgcn_s_barrier();

    // ---- steady phases 0..5
    for (int t = 0; t < HDIM / 64 - 2; t += 2) {        // t = 0,2,4
        // phase t (buf 0)
        STAGEA(t + 1, 1);   SBAR();
        LOADB(t + 2, rB0);  SBAR();
        COMPUTE(0);
        asm volatile("s_waitcnt vmcnt(12)" ::: "memory");  // LOADB(t+1) -> rB1
        SBAR();
        WRITEB(1, rB1);     SBAR();
        asm volatile("s_waitcnt vmcnt(8) lgkmcnt(0)" ::: "memory");
        SBAR();
        __builtin_amdgcn_s_barrier();
        // phase t+1 (buf 1)
        STAGEA(t + 2, 0);   SBAR();
        LOADB(t + 3, rB1);  SBAR();
        COMPUTE(1);
        asm volatile("s_waitcnt vmcnt(12)" ::: "memory");  // LOADB(t+2) -> rB0
        SBAR();
        WRITEB(0, rB0);     SBAR();
        asm volatile("s_waitcnt vmcnt(8) lgkmcnt(0)" ::: "memory");
        SBAR();
        __builtin_amdgcn_s_barrier();
    }

    // ---- phase 6 (buf 0): leftover LOADB(7) in rB1
    STAGEA(7, 1);   SBAR();
    COMPUTE(0);
    asm volatile("s_waitcnt vmcnt(4)" ::: "memory");   // LOADB(7) done
    SBAR();
    WRITEB(1, rB1); SBAR();
    asm volatile("s_waitcnt vmcnt(0) lgkmcnt(0)" ::: "memory");
    SBAR();
    __builtin_amdgcn_s_barrier();
    // ---- phase 7 (buf 1)
    COMPUTE(1);

    const int dcol0 = nt * 128 + wc * 64;
    #pragma unroll
    for (int m = 0; m < 4; ++m) {
        #pragma unroll
        for (int n = 0; n < 4; ++n) {
            #pragma unroll
            for (int i = 0; i < 4; ++i) {
                int row = tok0 + wr * 64 + m * 16 + (lane >> 4) * 4 + i;
                int col = dcol0 + n * 16 + (lane & 15);
                Out[(size_t)row * DDIM + col] = acc[m][n][i];
            }
        }
    }
}

extern "C" void kernel_launch(void* const* d_in, const int* in_sizes, int n_in,
                              void* d_out, int out_size, void* d_ws, size_t ws_size,
                              hipStream_t stream) {
    const float* X   = (const float*)d_in[0];   // (T, D) fp32
    const float* S   = (const float*)d_in[1];   // (T, D/32) fp32
    const float* W13 = (const float*)d_in[4];   // (E, 2H, D) fp32
    const float* W2  = (const float*)d_in[5];   // (E, D, H) fp32
    float* Out = (float*)d_out;                 // (T, D) fp32

    // workspace: Hb bf16 (T*H) = 8 MiB.
    // Xb (T*D bf16 = 16 MiB) lives in d_out's first half: gemm1 consumes it,
    // then gemm2 overwrites all of d_out with the final fp32 output.
    __hip_bfloat16* Hb = (__hip_bfloat16*)d_ws;
    unsigned short* Xb = (unsigned short*)d_out;

    convert_x_kernel<<<2048, 256, 0, stream>>>(X, S, Xb);
    gemm1_silu_kernel<<<NE * 4 * 8, 512, 0, stream>>>(Xb, W13, Hb);
    gemm2_kernel<<<NE * 8 * 8, 256, 0, stream>>>(Hb, W2, Out);
}

// Round 19
// 54.586 us; speedup vs baseline: 1.0925x; 1.0165x over previous
//
#include <hip/hip_runtime.h>
#include <hip/hip_bf16.h>

// Problem constants (match reference)
#define T_TOK 8192
#define DDIM  1024
#define HDIM  512
#define NE    8
#define TPE   (T_TOK / NE)   // 1024 tokens per expert (static partition per reference)

typedef __attribute__((ext_vector_type(4))) float floatx4;
typedef __attribute__((ext_vector_type(8))) short bf16x8;

#define SBAR() __builtin_amdgcn_sched_barrier(0)

__device__ __forceinline__ unsigned short f2bf(float f) {
    union { float f; unsigned int u; } v;
    v.f = f;
    unsigned int u = v.u;
    unsigned int r = u + 0x7FFFu + ((u >> 16) & 1u);  // RNE
    return (unsigned short)(r >> 16);
}

// packed f32x2 -> bf16x2 (RNE), single instruction
__device__ __forceinline__ unsigned int cvt_pk_bf16(float lo, float hi) {
    unsigned int r;
    asm("v_cvt_pk_bf16_f32 %0, %1, %2" : "=v"(r) : "v"(lo), "v"(hi));
    return r;
}

// async global -> LDS, 16 bytes per lane (dest must be linear: base + lane*16)
__device__ __forceinline__ void gld_lds16(const void* g, void* l) {
    __builtin_amdgcn_global_load_lds(
        (const __attribute__((address_space(1))) unsigned int*)g,
        (__attribute__((address_space(3))) unsigned int*)l, 16, 0, 0);
}

// ---------------------------------------------------------------------------
// Kernel 0 (streaming): X*scale -> bf16 only (48 MB round trip, BW floor).
// ---------------------------------------------------------------------------
__global__ __launch_bounds__(256)
void convert_x_kernel(const float* __restrict__ X, const float* __restrict__ S,
                      unsigned short* __restrict__ Xb)
{
    const int NTX = (T_TOK * DDIM) / 4;            // 2,097,152 float4 chunks
    const int stride = gridDim.x * blockDim.x;
    for (int i = blockIdx.x * blockDim.x + threadIdx.x; i < NTX; i += stride) {
        int row = i >> 8;            // D/4 = 256 chunks per row
        int c4  = i & 255;
        float4 v = reinterpret_cast<const float4*>(X)[i];
        float sc = S[row * (DDIM / 32) + (c4 >> 3)];
        ushort4 b;
        b.x = f2bf(v.x * sc); b.y = f2bf(v.y * sc);
        b.z = f2bf(v.z * sc); b.w = f2bf(v.w * sc);
        reinterpret_cast<ushort4*>(Xb)[i] = b;
    }
}

// XCD-aware swizzles (nwg % 8 == 0 -> bijective)
__device__ __forceinline__ int xcd_swizzle_512(int raw) {
    return (raw & 7) * 64 + (raw >> 3);
}
__device__ __forceinline__ int xcd_swizzle_256(int raw) {
    return (raw & 7) * 32 + (raw >> 3);
}

// LDS tile layout: [rows][8 slots of 16B]. Bank-conflict swizzle (T2/G21):
//   phys 16B-slot = logical_slot ^ (row & 7)
//   - gld_lds path: LDS dest LINEAR, global SOURCE slot pre-permuted.
//   - reg-staged path: ds_write directly to the swizzled slot.
//   - ds_read applies the same XOR.

// ---------------------------------------------------------------------------
// Kernel 1: h = silu(Xb W1^T) * (Xb W3^T).  BM=256, BN=64, BK=64, 512 thr.
// ROUND-19: exact revert to the round-15 configuration (measured best,
// 54.4 us total). Rounds 10-18 A/B'd every catalog lever on this kernel
// (schedule depth, occupancy, tile, B-dtype, block order, traffic placement);
// all landed 54.4-56. nt-fastest ordering, write-late single-barrier phase.
// A = Xb bf16 via gld_lds (sA dbuf 64 KB); B = W13 fp32 reg-staged depth-2
// (rB0/rB1, 4 float4 each), cvt_pk -> swizzled ds_write (sB dbuf 32 KB).
// LDS 96 KB -> 1 block/CU, 8 waves. Phase:
//   STAGEA(t+1,buf^1)[4] ; LOADB(t+2)[4] ; COMPUTE(t) ;
//   vmcnt(8)  [LOADB(t+1) landed] ; WRITEB(t+1) ;
//   vmcnt(4)+lgkmcnt(0) [STAGEA(t+1) done; LOADB(t+2) airborne] ; s_barrier
// grid = 8e * 4mt * 8nt = 256 blocks.
// ---------------------------------------------------------------------------
__global__ __launch_bounds__(512, 2)
void gemm1_silu_kernel(const unsigned short* __restrict__ Xb,
                       const float* __restrict__ W13,
                       __hip_bfloat16* __restrict__ Hout)
{
    const int bid = xcd_swizzle_256(blockIdx.x);
    const int e  = bid >> 5;
    const int mt = (bid >> 3) & 3;    // token tile (256 rows)
    const int nt = bid & 7;           // h tile (64 cols)
    const int tok0 = e * TPE + mt * 256;
    const float* __restrict__ We = W13 + (size_t)e * (2 * HDIM) * DDIM;

    __shared__ __hip_bfloat16 sA[2][256][64];   // 64 KB
    __shared__ __hip_bfloat16 sB[2][128][64];   // 32 KB

    const int tid  = threadIdx.x;
    const int lane = tid & 63;
    const int wave = tid >> 6;   // 0..7
    const int wr = wave >> 1;    // 0..3 (M quarter: 64 rows)
    const int wc = wave & 1;     // 0..1 (N: 32 cols each)
    const int lr = lane & 15;
    const int sw0 = ((lane >> 4) ^ (lane & 7));

    floatx4 acc1[4][2] = {};
    floatx4 acc3[4][2] = {};

    // A staging: 256x64 bf16 = 2048 x 16B chunks / 512 thr = 4 each
    const int srowA = tid >> 3;                          // 0..63
    const int dcolA = (tid & 7) * 8;                     // LDS linear dest
    const int gcolA = ((tid & 7) ^ (srowA & 7)) * 8;     // pre-swizzled source
    // B load: 128 rows x 16 float4 / 512 thr = 4 each
    const int srowB = tid >> 4;                          // 0..31
    const int f4    = tid & 15;                          // float4 slot in row
    const int bcol  = f4 * 4;                            // fp32 col

    float4 rB0[4], rB1[4];

    auto LOADB = [&](int kk, float4* rB) {   // 4 VM ops, fp32 W13 (w1|w3 rows)
        const int k0 = kk * 64;
        #pragma unroll
        for (int j = 0; j < 4; ++j) {
            int row = srowB + j * 32;        // 0..127; row&7 const under +32
            int wrow = (j < 2) ? (nt * 64 + row)                 // w1 rows
                               : (HDIM + nt * 64 + (row - 64));  // w3 rows
            rB[j] = *reinterpret_cast<const float4*>(
                        &We[(size_t)wrow * DDIM + k0 + bcol]);
        }
    };
    auto STAGEA = [&](int kk, int buf) {     // 4 VM ops (gld_lds)
        const int k0 = kk * 64;
        #pragma unroll
        for (int j = 0; j < 4; ++j) {
            int row = srowA + j * 64;        // row&7 const under +64
            gld_lds16(&Xb[(size_t)(tok0 + row) * DDIM + k0 + gcolA],
                      &sA[buf][row][dcolA]);
        }
    };
    auto WRITEB = [&](int buf, const float4* rB) {   // cvt + swizzled ds_write_b64
        #pragma unroll
        for (int j = 0; j < 4; ++j) {
            int row = srowB + j * 32;
            uint2 w;
            w.x = cvt_pk_bf16(rB[j].x, rB[j].y);
            w.y = cvt_pk_bf16(rB[j].z, rB[j].w);
            char* base = reinterpret_cast<char*>(&sB[buf][row][0]);
            int off = (((f4 >> 1) ^ (row & 7)) << 4) + ((f4 & 1) << 3);
            *reinterpret_cast<uint2*>(base + off) = w;
        }
    };
    auto COMPUTE_KS = [&](int buf, int ks) {
        const int rc = (sw0 ^ (ks << 2)) << 3;   // swizzled read col
        bf16x8 a[4], b1[2], b3[2];
        #pragma unroll
        for (int m = 0; m < 4; ++m)
            a[m] = *reinterpret_cast<const bf16x8*>(&sA[buf][wr * 64 + m * 16 + lr][rc]);
        #pragma unroll
        for (int n = 0; n < 2; ++n) {
            b1[n] = *reinterpret_cast<const bf16x8*>(&sB[buf][wc * 32 + n * 16 + lr][rc]);
            b3[n] = *reinterpret_cast<const bf16x8*>(&sB[buf][64 + wc * 32 + n * 16 + lr][rc]);
        }
        #pragma unroll
        for (int m = 0; m < 4; ++m)
            #pragma unroll
            for (int n = 0; n < 2; ++n) {
                acc1[m][n] = __builtin_amdgcn_mfma_f32_16x16x32_bf16(a[m], b1[n], acc1[m][n], 0, 0, 0);
                acc3[m][n] = __builtin_amdgcn_mfma_f32_16x16x32_bf16(a[m], b3[n], acc3[m][n], 0, 0, 0);
            }
    };

    // ---- prologue: VM order [LOADB(0) 4][STAGEA(0) 4][LOADB(1) 4]
    LOADB(0, rB0);  SBAR();
    STAGEA(0, 0);   SBAR();
    LOADB(1, rB1);  SBAR();
    asm volatile("s_waitcnt vmcnt(8)" ::: "memory");   // LOADB(0) done
    SBAR();
    WRITEB(0, rB0); SBAR();
    asm volatile("s_waitcnt vmcnt(4) lgkmcnt(0)" ::: "memory"); // STAGEA(0)+writes
    SBAR();
    __builtin_amdgcn_s_barrier();
    // entering steady state: outstanding VM = LOADB(1) [4]

    // ---- steady phases 0..13 (even/odd pairs; static rB names)
    for (int t = 0; t < DDIM / 64 - 2; t += 2) {        // t = 0,2,...,12
        // phase t (buf 0): rB1 holds tile t+1 (in flight)
        STAGEA(t + 1, 1);   SBAR();
        LOADB(t + 2, rB0);  SBAR();
        COMPUTE_KS(0, 0);
        COMPUTE_KS(0, 1);
        asm volatile("s_waitcnt vmcnt(8)" ::: "memory");  // LOADB(t+1) -> rB1 ready
        SBAR();
        WRITEB(1, rB1);     SBAR();
        asm volatile("s_waitcnt vmcnt(4) lgkmcnt(0)" ::: "memory"); // STAGEA(t+1)
        SBAR();
        __builtin_amdgcn_s_barrier();
        // phase t+1 (buf 1): rB0 holds tile t+2 (in flight)
        STAGEA(t + 2, 0);   SBAR();
        LOADB(t + 3, rB1);  SBAR();
        COMPUTE_KS(1, 0);
        COMPUTE_KS(1, 1);
        asm volatile("s_waitcnt vmcnt(8)" ::: "memory");  // LOADB(t+2) -> rB0 ready
        SBAR();
        WRITEB(0, rB0);     SBAR();
        asm volatile("s_waitcnt vmcnt(4) lgkmcnt(0)" ::: "memory"); // STAGEA(t+2)
        SBAR();
        __builtin_amdgcn_s_barrier();
    }

    // ---- phase 14 (buf 0): rB1 holds LOADB(15); no more LOADB
    STAGEA(15, 1);    SBAR();
    COMPUTE_KS(0, 0);
    COMPUTE_KS(0, 1);
    asm volatile("s_waitcnt vmcnt(4)" ::: "memory");   // LOADB(15) done
    SBAR();
    WRITEB(1, rB1);   SBAR();
    asm volatile("s_waitcnt vmcnt(0) lgkmcnt(0)" ::: "memory"); // STAGEA(15)
    SBAR();
    __builtin_amdgcn_s_barrier();
    // ---- phase 15 (buf 1)
    COMPUTE_KS(1, 0);
    COMPUTE_KS(1, 1);

    // ---- epilogue: h = silu(h1) * h3 -> bf16
    const int hcol0 = nt * 64 + wc * 32;
    #pragma unroll
    for (int m = 0; m < 4; ++m) {
        #pragma unroll
        for (int n = 0; n < 2; ++n) {
            #pragma unroll
            for (int i = 0; i < 4; ++i) {
                int row = tok0 + wr * 64 + m * 16 + (lane >> 4) * 4 + i;
                int col = hcol0 + n * 16 + (lane & 15);
                float h1 = acc1[m][n][i];
                float h3 = acc3[m][n][i];
                float sig = 1.0f / (1.0f + __expf(-h1));
                Hout[(size_t)row * HDIM + col] = __float2bfloat16(h1 * sig * h3);
            }
        }
    }
}

// ---------------------------------------------------------------------------
// Kernel 2: out = h W2^T.  (round-11..18 form, near its L2/HBM floor)
// A = Hb bf16 via gld_lds; B = W2 fp32->bf16 reg-staged depth-2, write-late.
// ---------------------------------------------------------------------------
__global__ __launch_bounds__(256, 2)
void gemm2_kernel(const __hip_bfloat16* __restrict__ Hin,
                  const float* __restrict__ W2,
                  float* __restrict__ Out)
{
    const int bid = xcd_swizzle_512(blockIdx.x);
    const int e  = bid >> 6;
    const int nt = (bid >> 3) & 7;    // d tile -- major (W2 tile reused)
    const int mt = bid & 7;           // token tile -- fastest (stream Hb)
    const int tok0 = e * TPE + mt * 128;
    const float* __restrict__ We = W2 + (size_t)e * DDIM * HDIM;

    __shared__ __hip_bfloat16 sA[2][128][64];
    __shared__ __hip_bfloat16 sB[2][128][64];

    const int tid  = threadIdx.x;
    const int lane = tid & 63;
    const int wave = tid >> 6;
    const int wr = wave >> 1;
    const int wc = wave & 1;
    const int lr = lane & 15;
    const int sw0 = ((lane >> 4) ^ (lane & 7));

    floatx4 acc[4][4] = {};

    const int srow0 = (tid >> 3);
    const int c8    = (tid & 7) * 8;
    const int dcol  = (tid & 7) * 8;
    const int swcol = ((tid & 7) ^ (srow0 & 7)) * 8;

    float4 rB0[8], rB1[8];

    auto LOADB = [&](int kk, float4* rB) {  // 8 VM ops
        const int k0 = kk * 64;
        #pragma unroll
        for (int j = 0; j < 4; ++j) {
            int row = srow0 + j * 32;
            const float* p = &We[(size_t)(nt * 128 + row) * HDIM + k0 + c8];
            rB[2*j]   = *reinterpret_cast<const float4*>(p);
            rB[2*j+1] = *reinterpret_cast<const float4*>(p + 4);
        }
    };
    auto STAGEA = [&](int kk, int buf) {    // 4 VM ops (gld_lds)
        const int k0 = kk * 64;
        #pragma unroll
        for (int j = 0; j < 4; ++j) {
            int row = srow0 + j * 32;
            gld_lds16(&Hin[(size_t)(tok0 + row) * HDIM + k0 + swcol],
                      &sA[buf][row][dcol]);
        }
    };
    auto WRITEB = [&](int buf, const float4* rB) {
        #pragma unroll
        for (int j = 0; j < 4; ++j) {
            int row = srow0 + j * 32;
            uint4 w;
            w.x = cvt_pk_bf16(rB[2*j].x,   rB[2*j].y);
            w.y = cvt_pk_bf16(rB[2*j].z,   rB[2*j].w);
            w.z = cvt_pk_bf16(rB[2*j+1].x, rB[2*j+1].y);
            w.w = cvt_pk_bf16(rB[2*j+1].z, rB[2*j+1].w);
            *reinterpret_cast<uint4*>(&sB[buf][row][swcol]) = w;
        }
    };
    auto COMPUTE = [&](int buf) {
        #pragma unroll
        for (int ks = 0; ks < 2; ++ks) {
            const int rc = (sw0 ^ (ks << 2)) << 3;
            bf16x8 a[4], b[4];
            #pragma unroll
            for (int m = 0; m < 4; ++m)
                a[m] = *reinterpret_cast<const bf16x8*>(&sA[buf][wr * 64 + m * 16 + lr][rc]);
            #pragma unroll
            for (int n = 0; n < 4; ++n)
                b[n] = *reinterpret_cast<const bf16x8*>(&sB[buf][wc * 64 + n * 16 + lr][rc]);
            #pragma unroll
            for (int m = 0; m < 4; ++m)
                #pragma unroll
                for (int n = 0; n < 4; ++n)
                    acc[m][n] = __builtin_amdgcn_mfma_f32_16x16x32_bf16(a[m], b[n], acc[m][n], 0, 0, 0);
        }
    };

    // ---- prologue
    LOADB(0, rB0);  SBAR();
    STAGEA(0, 0);   SBAR();
    LOADB(1, rB1);  SBAR();
    asm volatile("s_waitcnt vmcnt(12)" ::: "memory");  // LOADB(0) done
    SBAR();
    WRITEB(0, rB0); SBAR();
    asm volatile("s_waitcnt vmcnt(8) lgkmcnt(0)" ::: "memory");
    SBAR();
    __builtin_amdgcn_s_barrier();

    // ---- steady phases 0..5
    for (int t = 0; t < HDIM / 64 - 2; t += 2) {        // t = 0,2,4
        // phase t (buf 0)
        STAGEA(t + 1, 1);   SBAR();
        LOADB(t + 2, rB0);  SBAR();
        COMPUTE(0);
        asm volatile("s_waitcnt vmcnt(12)" ::: "memory");  // LOADB(t+1) -> rB1
        SBAR();
        WRITEB(1, rB1);     SBAR();
        asm volatile("s_waitcnt vmcnt(8) lgkmcnt(0)" ::: "memory");
        SBAR();
        __builtin_amdgcn_s_barrier();
        // phase t+1 (buf 1)
        STAGEA(t + 2, 0);   SBAR();
        LOADB(t + 3, rB1);  SBAR();
        COMPUTE(1);
        asm volatile("s_waitcnt vmcnt(12)" ::: "memory");  // LOADB(t+2) -> rB0
        SBAR();
        WRITEB(0, rB0);     SBAR();
        asm volatile("s_waitcnt vmcnt(8) lgkmcnt(0)" ::: "memory");
        SBAR();
        __builtin_amdgcn_s_barrier();
    }

    // ---- phase 6 (buf 0): leftover LOADB(7) in rB1
    STAGEA(7, 1);   SBAR();
    COMPUTE(0);
    asm volatile("s_waitcnt vmcnt(4)" ::: "memory");   // LOADB(7) done
    SBAR();
    WRITEB(1, rB1); SBAR();
    asm volatile("s_waitcnt vmcnt(0) lgkmcnt(0)" ::: "memory");
    SBAR();
    __builtin_amdgcn_s_barrier();
    // ---- phase 7 (buf 1)
    COMPUTE(1);

    const int dcol0 = nt * 128 + wc * 64;
    #pragma unroll
    for (int m = 0; m < 4; ++m) {
        #pragma unroll
        for (int n = 0; n < 4; ++n) {
            #pragma unroll
            for (int i = 0; i < 4; ++i) {
                int row = tok0 + wr * 64 + m * 16 + (lane >> 4) * 4 + i;
                int col = dcol0 + n * 16 + (lane & 15);
                Out[(size_t)row * DDIM + col] = acc[m][n][i];
            }
        }
    }
}

extern "C" void kernel_launch(void* const* d_in, const int* in_sizes, int n_in,
                              void* d_out, int out_size, void* d_ws, size_t ws_size,
                              hipStream_t stream) {
    const float* X   = (const float*)d_in[0];   // (T, D) fp32
    const float* S   = (const float*)d_in[1];   // (T, D/32) fp32
    const float* W13 = (const float*)d_in[4];   // (E, 2H, D) fp32
    const float* W2  = (const float*)d_in[5];   // (E, D, H) fp32
    float* Out = (float*)d_out;                 // (T, D) fp32

    // workspace: Hb bf16 (T*H) = 8 MiB.
    // Xb (T*D bf16 = 16 MiB) lives in d_out's first half: gemm1 consumes it,
    // then gemm2 overwrites all of d_out with the final fp32 output.
    __hip_bfloat16* Hb = (__hip_bfloat16*)d_ws;
    unsigned short* Xb = (unsigned short*)d_out;

    convert_x_kernel<<<2048, 256, 0, stream>>>(X, S, Xb);
    gemm1_silu_kernel<<<NE * 4 * 8, 512, 0, stream>>>(Xb, W13, Hb);
    gemm2_kernel<<<NE * 8 * 8, 256, 0, stream>>>(Hb, W2, Out);
}